// Round 5
// baseline (45.041 us; speedup 1.0000x reference)
//
#include <hip/hip_runtime.h>

// CantileverPINN: loss = mean((d4/dx4 w(x) - 1)^2), w = MLP 1->15->30->60->1 tanh.
// w_xxxx(x) is analytic on [0,1]: evaluate exact fp32 jets at 64 Chebyshev nodes,
// then per-point degree-63 Chebyshev (Clenshaw). Two kernels total:
//  K1: 64 nodes, wave-per-node (16 blocks x 256) + zero the done-counter
//  K3: per-block DCT (cheap, hidden) + Clenshaw + block reduce + last-block-done
//      final reduction (device-scope atomics, fixed-order sum -> deterministic)

#define M_NODES 64

__device__ __forceinline__ float cos_turns(float phi) {   // cos(2*pi*phi)
    float r;
    asm("v_cos_f32 %0, %1" : "=v"(r) : "v"(phi));
    return r;
}

__device__ __forceinline__ float fast_tanh(float u) {
    float e = __expf(2.0f * u);
    return 1.0f - 2.0f / (e + 1.0f);   // e=inf -> 1, e=0 -> -1
}

struct TanhD { float t, s, p2, p3, p4; };

__device__ __forceinline__ TanhD tanh_derivs(float u0) {
    TanhD d;
    float t = fast_tanh(u0);
    float s = fmaf(-t, t, 1.0f);
    float ts = t * s;
    float t2 = t * t;
    d.t = t;
    d.s = s;
    d.p2 = -2.0f * ts;
    d.p3 = s * fmaf(4.0f, t2, -2.0f * s);          // s(4t^2 - 2s)
    d.p4 = 8.0f * ts * fmaf(-1.0f, t2, 2.0f * s);  // 8ts(2s - t^2)
    return d;
}

__device__ __forceinline__ void tanh_jet(const float u[5], float f[5]) {
    TanhD d = tanh_derivs(u[0]);
    float u1 = u[1], u2 = u[2], u3 = u[3], u4 = u[4];
    float u1sq = u1 * u1;
    f[0] = d.t;
    f[1] = d.s * u1;
    f[2] = fmaf(d.p2, u1sq, d.s * u2);
    f[3] = fmaf(d.p3, u1sq * u1, fmaf(3.0f * d.p2, u1 * u2, d.s * u3));
    f[4] = fmaf(d.p4, u1sq * u1sq,
           fmaf(6.0f * d.p3, u1sq * u2,
           fmaf(3.0f * d.p2, u2 * u2,
           fmaf(4.0f * d.p2, u1 * u3, d.s * u4))));
}

__device__ __forceinline__ float tanh_jet_d4(float u0, float u1, float u2,
                                             float u3, float u4) {
    TanhD d = tanh_derivs(u0);
    const float u1sq = u1 * u1;
    return fmaf(d.p4, u1sq * u1sq,
           fmaf(6.0f * d.p3, u1sq * u2,
           fmaf(3.0f * d.p2, u2 * u2,
           fmaf(4.0f * d.p2, u1 * u3, d.s * u4))));
}

// ---- K1: w_xxxx at 64 Chebyshev nodes, one wave per node. 16 blocks x 256. ----
__global__ __launch_bounds__(256, 1)
void pinn_node_kernel(const float* __restrict__ W1, const float* __restrict__ b1,
                      const float* __restrict__ W2, const float* __restrict__ b2,
                      const float* __restrict__ W3, const float* __restrict__ b3,
                      const float* __restrict__ W4,
                      float* __restrict__ f_nodes, unsigned int* __restrict__ counter) {
    __shared__ float sW1[15], sB1[15], sB2[30], sB3[60], sW4[60];
    __shared__ float sW2[15 * 30];    // [i][j], lane j reads stride-1
    __shared__ float sW3[30 * 60];    // [i][m], lane m reads stride-1
    __shared__ float gj[4][15][5];    // L1 jets per node
    __shared__ float h2[4][30][5];    // h2 jets per node

    const int t = threadIdx.x;
    if (blockIdx.x == 0 && t == 0)
        __hip_atomic_store(counter, 0u, __ATOMIC_RELAXED, __HIP_MEMORY_SCOPE_AGENT);

    for (int idx = t; idx < 450; idx += 256) sW2[idx] = W2[idx];
    for (int idx = t; idx < 1800; idx += 256) sW3[idx] = W3[idx];
    if (t < 15) { sW1[t] = W1[t]; sB1[t] = b1[t]; }
    if (t < 30) sB2[t] = b2[t];
    if (t < 60) { sB3[t] = b3[t]; sW4[t] = W4[t]; }
    __syncthreads();

    const int nd   = t >> 6;                      // node within block (0..3)
    const int lane = t & 63;
    const int node = blockIdx.x * 4 + nd;         // 0..63

    // x = 0.5 + 0.5*cos(pi*(node+0.5)/64); turns = (2*node+1)/256 exact
    const float phi = (float)(2 * node + 1) * (1.0f / 256.0f);
    const float xi  = fmaf(0.5f, cos_turns(phi), 0.5f);

    // phase 0: lanes 0..14 compute L1 jets
    if (lane < 15) {
        const float w = sW1[lane];
        TanhD d = tanh_derivs(fmaf(w, xi, sB1[lane]));
        const float w2 = w * w;
        gj[nd][lane][0] = d.t;
        gj[nd][lane][1] = d.s * w;
        gj[nd][lane][2] = d.p2 * w2;
        gj[nd][lane][3] = d.p3 * w2 * w;
        gj[nd][lane][4] = d.p4 * w2 * w2;
    }
    __syncthreads();

    // phase A: lanes 0..29 compute h2 jets (broadcast gj, stride-1 W2)
    if (lane < 30) {
        float z[5] = { sB2[lane], 0.0f, 0.0f, 0.0f, 0.0f };
        for (int i = 0; i < 15; ++i) {
            const float wij = sW2[i * 30 + lane];
            #pragma unroll
            for (int k = 0; k < 5; ++k) z[k] = fmaf(wij, gj[nd][i][k], z[k]);
        }
        float h[5];
        tanh_jet(z, h);
        #pragma unroll
        for (int k = 0; k < 5; ++k) h2[nd][lane][k] = h[k];
    }
    __syncthreads();

    // phase B: lanes 0..59 compute z3 jets, d4, dot with W4
    float v = 0.0f;
    if (lane < 60) {
        float z[5] = { sB3[lane], 0.0f, 0.0f, 0.0f, 0.0f };
        for (int i = 0; i < 30; ++i) {
            const float wim = sW3[i * 60 + lane];
            #pragma unroll
            for (int k = 0; k < 5; ++k) z[k] = fmaf(wim, h2[nd][i][k], z[k]);
        }
        v = sW4[lane] * tanh_jet_d4(z[0], z[1], z[2], z[3], z[4]);
    }
    #pragma unroll
    for (int off = 32; off > 0; off >>= 1) v += __shfl_down(v, off, 64);
    if (lane == 0) f_nodes[node] = v;
}

// ---- K3: per-block DCT + Clenshaw + block reduce + last-block final reduce ----
__global__ __launch_bounds__(256, 4)
void pinn_eval_kernel(const float* __restrict__ x,
                      const float* __restrict__ f_nodes,
                      float* __restrict__ partials,
                      unsigned int* __restrict__ counter,
                      float* __restrict__ out, int n, float inv_n) {
    __shared__ float sf[M_NODES];
    __shared__ float sc[M_NODES];
    __shared__ float wsum[4];
    __shared__ bool sdone;

    const int t = threadIdx.x;
    const int gid = blockIdx.x * 256 + t;
    const float xi = (gid < n) ? x[gid] : 0.0f;     // issue global load early

    if (t < M_NODES) sf[t] = f_nodes[t];
    __syncthreads();
    if (t < M_NODES) {
        float s = 0.0f;
        for (int j = 0; j < M_NODES; ++j) {
            // cos(pi*t*(j+0.5)/64) = cos(2*pi*(t*(2j+1) mod 256)/256), exact
            const int num = (t * (2 * j + 1)) & 255;
            s = fmaf(sf[j], cos_turns((float)num * (1.0f / 256.0f)), s);
        }
        sc[t] = s * ((t == 0) ? (1.0f / 64.0f) : (2.0f / 64.0f));
    }
    __syncthreads();

    // Clenshaw, degree 63
    const float tt = fmaf(2.0f, xi, -1.0f);
    const float t2 = tt + tt;
    float b1 = 0.0f, b2 = 0.0f;
    #pragma unroll 4
    for (int k = M_NODES - 1; k >= 1; --k) {
        const float bn = fmaf(t2, b1, sc[k] - b2);
        b2 = b1; b1 = bn;
    }
    const float fv = fmaf(tt, b1, sc[0] - b2);      // w_xxxx(x)

    const float r = fv - 1.0f;                      // P/(E*I) = 1
    float val = (gid < n) ? r * r : 0.0f;

    #pragma unroll
    for (int off = 32; off > 0; off >>= 1) val += __shfl_down(val, off, 64);
    if ((t & 63) == 0) wsum[t >> 6] = val;
    __syncthreads();
    if (t == 0) {
        const float psum = wsum[0] + wsum[1] + wsum[2] + wsum[3];
        __hip_atomic_store(&partials[blockIdx.x], psum,
                           __ATOMIC_RELEASE, __HIP_MEMORY_SCOPE_AGENT);
        const unsigned int old = __hip_atomic_fetch_add(
            counter, 1u, __ATOMIC_ACQ_REL, __HIP_MEMORY_SCOPE_AGENT);
        sdone = (old == (unsigned int)(gridDim.x - 1));
    }
    __syncthreads();

    if (sdone) {                                    // exactly one block per call
        const int nblocks = (int)gridDim.x;
        float v = 0.0f;
        for (int i = t; i < nblocks; i += 256)
            v += __hip_atomic_load(&partials[i],
                                   __ATOMIC_RELAXED, __HIP_MEMORY_SCOPE_AGENT);
        #pragma unroll
        for (int off = 32; off > 0; off >>= 1) v += __shfl_down(v, off, 64);
        if ((t & 63) == 0) wsum[t >> 6] = v;
        __syncthreads();
        if (t == 0) out[0] = (wsum[0] + wsum[1] + wsum[2] + wsum[3]) * inv_n;
    }
}

extern "C" void kernel_launch(void* const* d_in, const int* in_sizes, int n_in,
                              void* d_out, int out_size, void* d_ws, size_t ws_size,
                              hipStream_t stream) {
    const float* x  = (const float*)d_in[0];
    const float* W1 = (const float*)d_in[1];
    const float* b1 = (const float*)d_in[2];
    const float* W2 = (const float*)d_in[3];
    const float* b2 = (const float*)d_in[4];
    const float* W3 = (const float*)d_in[5];
    const float* b3 = (const float*)d_in[6];
    const float* W4 = (const float*)d_in[7];
    // d_in[8] = b4: constant offset; vanishes under d^4/dx^4.

    const int n = in_sizes[0];
    const int nblocks = (n + 255) / 256;

    float* ws        = (float*)d_ws;
    float* f_nodes   = ws;                          // 64 floats
    float* partials  = ws + M_NODES;                // nblocks floats
    unsigned int* counter = (unsigned int*)(ws + M_NODES + nblocks);

    pinn_node_kernel<<<16, 256, 0, stream>>>(W1, b1, W2, b2, W3, b3, W4,
                                             f_nodes, counter);
    pinn_eval_kernel<<<nblocks, 256, 0, stream>>>(x, f_nodes, partials, counter,
                                                  (float*)d_out, n,
                                                  1.0f / (float)n);
}

// Round 6
// 18.291 us; speedup vs baseline: 2.4624x; 2.4624x over previous
//
#include <hip/hip_runtime.h>

// CantileverPINN: loss = mean((d4/dx4 w(x) - 1)^2), w = MLP 1->15->30->60->1 tanh.
// w_xxxx(x) is analytic on [0,1]: exact fp32 4th-order jets at 64 Chebyshev
// nodes, DCT -> coefficients, per-point degree-63 Clenshaw. Four kernels, no
// device-scope atomics (kernel boundaries provide coherence):
//  K1: 64 nodes, wave-per-node (16 blocks x 256)
//  K2: DCT (1 block x 64)
//  K3: Clenshaw + block reduce -> partials (1024 blocks x 256)
//  K4: final reduce -> out

#define M_NODES 64

__device__ __forceinline__ float cos_turns(float phi) {   // cos(2*pi*phi)
    float r;
    asm("v_cos_f32 %0, %1" : "=v"(r) : "v"(phi));
    return r;
}

__device__ __forceinline__ float fast_tanh(float u) {
    float e = __expf(2.0f * u);
    return 1.0f - 2.0f / (e + 1.0f);   // e=inf -> 1, e=0 -> -1
}

struct TanhD { float t, s, p2, p3, p4; };

__device__ __forceinline__ TanhD tanh_derivs(float u0) {
    TanhD d;
    float t = fast_tanh(u0);
    float s = fmaf(-t, t, 1.0f);
    float ts = t * s;
    float t2 = t * t;
    d.t = t;
    d.s = s;
    d.p2 = -2.0f * ts;
    d.p3 = s * fmaf(4.0f, t2, -2.0f * s);          // s(4t^2 - 2s)
    d.p4 = 8.0f * ts * fmaf(-1.0f, t2, 2.0f * s);  // 8ts(2s - t^2)
    return d;
}

__device__ __forceinline__ void tanh_jet(const float u[5], float f[5]) {
    TanhD d = tanh_derivs(u[0]);
    float u1 = u[1], u2 = u[2], u3 = u[3], u4 = u[4];
    float u1sq = u1 * u1;
    f[0] = d.t;
    f[1] = d.s * u1;
    f[2] = fmaf(d.p2, u1sq, d.s * u2);
    f[3] = fmaf(d.p3, u1sq * u1, fmaf(3.0f * d.p2, u1 * u2, d.s * u3));
    f[4] = fmaf(d.p4, u1sq * u1sq,
           fmaf(6.0f * d.p3, u1sq * u2,
           fmaf(3.0f * d.p2, u2 * u2,
           fmaf(4.0f * d.p2, u1 * u3, d.s * u4))));
}

__device__ __forceinline__ float tanh_jet_d4(float u0, float u1, float u2,
                                             float u3, float u4) {
    TanhD d = tanh_derivs(u0);
    const float u1sq = u1 * u1;
    return fmaf(d.p4, u1sq * u1sq,
           fmaf(6.0f * d.p3, u1sq * u2,
           fmaf(3.0f * d.p2, u2 * u2,
           fmaf(4.0f * d.p2, u1 * u3, d.s * u4))));
}

// ---- K1: w_xxxx at 64 Chebyshev nodes, one wave per node. 16 blocks x 256. ----
__global__ __launch_bounds__(256, 1)
void pinn_node_kernel(const float* __restrict__ W1, const float* __restrict__ b1,
                      const float* __restrict__ W2, const float* __restrict__ b2,
                      const float* __restrict__ W3, const float* __restrict__ b3,
                      const float* __restrict__ W4,
                      float* __restrict__ f_nodes) {
    __shared__ float sW1[15], sB1[15], sB2[30], sB3[60], sW4[60];
    __shared__ float sW2[15 * 30];    // [i][j], lane j reads stride-1
    __shared__ float sW3[30 * 60];    // [i][m], lane m reads stride-1
    __shared__ float gj[4][15][5];    // L1 jets per node
    __shared__ float h2[4][30][5];    // h2 jets per node

    const int t = threadIdx.x;
    for (int idx = t; idx < 450; idx += 256) sW2[idx] = W2[idx];
    for (int idx = t; idx < 1800; idx += 256) sW3[idx] = W3[idx];
    if (t < 15) { sW1[t] = W1[t]; sB1[t] = b1[t]; }
    if (t < 30) sB2[t] = b2[t];
    if (t < 60) { sB3[t] = b3[t]; sW4[t] = W4[t]; }
    __syncthreads();

    const int nd   = t >> 6;                      // node within block (0..3)
    const int lane = t & 63;
    const int node = blockIdx.x * 4 + nd;         // 0..63

    // x = 0.5 + 0.5*cos(pi*(node+0.5)/64); turns = (2*node+1)/256 exact
    const float phi = (float)(2 * node + 1) * (1.0f / 256.0f);
    const float xi  = fmaf(0.5f, cos_turns(phi), 0.5f);

    // phase 0: lanes 0..14 compute L1 jets
    if (lane < 15) {
        const float w = sW1[lane];
        TanhD d = tanh_derivs(fmaf(w, xi, sB1[lane]));
        const float w2 = w * w;
        gj[nd][lane][0] = d.t;
        gj[nd][lane][1] = d.s * w;
        gj[nd][lane][2] = d.p2 * w2;
        gj[nd][lane][3] = d.p3 * w2 * w;
        gj[nd][lane][4] = d.p4 * w2 * w2;
    }
    __syncthreads();

    // phase A: lanes 0..29 compute h2 jets (broadcast gj, stride-1 W2)
    if (lane < 30) {
        float z[5] = { sB2[lane], 0.0f, 0.0f, 0.0f, 0.0f };
        for (int i = 0; i < 15; ++i) {
            const float wij = sW2[i * 30 + lane];
            #pragma unroll
            for (int k = 0; k < 5; ++k) z[k] = fmaf(wij, gj[nd][i][k], z[k]);
        }
        float h[5];
        tanh_jet(z, h);
        #pragma unroll
        for (int k = 0; k < 5; ++k) h2[nd][lane][k] = h[k];
    }
    __syncthreads();

    // phase B: lanes 0..59 compute z3 jets, d4, dot with W4
    float v = 0.0f;
    if (lane < 60) {
        float z[5] = { sB3[lane], 0.0f, 0.0f, 0.0f, 0.0f };
        for (int i = 0; i < 30; ++i) {
            const float wim = sW3[i * 60 + lane];
            #pragma unroll
            for (int k = 0; k < 5; ++k) z[k] = fmaf(wim, h2[nd][i][k], z[k]);
        }
        v = sW4[lane] * tanh_jet_d4(z[0], z[1], z[2], z[3], z[4]);
    }
    #pragma unroll
    for (int off = 32; off > 0; off >>= 1) v += __shfl_down(v, off, 64);
    if (lane == 0) f_nodes[node] = v;
}

// ---- K2: DCT-II -> Chebyshev coefficients. 1 block x 64 threads. ----
__global__ __launch_bounds__(64, 1)
void pinn_dct_kernel(const float* __restrict__ f_nodes,
                     float* __restrict__ coeffs) {
    __shared__ float sf[M_NODES];
    const int k = threadIdx.x;
    sf[k] = f_nodes[k];
    __syncthreads();
    float s = 0.0f;
    for (int j = 0; j < M_NODES; ++j) {
        // cos(pi*k*(j+0.5)/64) = cos(2*pi*(k*(2j+1) mod 256)/256), exact
        const int num = (k * (2 * j + 1)) & 255;
        s = fmaf(sf[j], cos_turns((float)num * (1.0f / 256.0f)), s);
    }
    coeffs[k] = s * ((k == 0) ? (1.0f / 64.0f) : (2.0f / 64.0f));
}

// ---- K3: Clenshaw eval per point + block reduction -> partials ----
__global__ __launch_bounds__(256, 4)
void pinn_eval_kernel(const float* __restrict__ x,
                      const float* __restrict__ coeffs,
                      float* __restrict__ partials, int n) {
    __shared__ float sc[M_NODES];
    __shared__ float wsum[4];
    const int t = threadIdx.x;
    const int gid = blockIdx.x * 256 + t;
    const float xi = (gid < n) ? x[gid] : 0.0f;     // issue global load early
    if (t < M_NODES) sc[t] = coeffs[t];
    __syncthreads();

    const float tt = fmaf(2.0f, xi, -1.0f);         // map [0,1] -> [-1,1]
    const float t2 = tt + tt;
    float b1 = 0.0f, b2 = 0.0f;
    #pragma unroll 4
    for (int k = M_NODES - 1; k >= 1; --k) {
        const float bn = fmaf(t2, b1, sc[k] - b2);
        b2 = b1; b1 = bn;
    }
    const float fv = fmaf(tt, b1, sc[0] - b2);      // w_xxxx(x)

    const float r = fv - 1.0f;                      // P/(E*I) = 1
    float val = (gid < n) ? r * r : 0.0f;

    #pragma unroll
    for (int off = 32; off > 0; off >>= 1) val += __shfl_down(val, off, 64);
    if ((t & 63) == 0) wsum[t >> 6] = val;
    __syncthreads();
    if (t == 0) partials[blockIdx.x] = wsum[0] + wsum[1] + wsum[2] + wsum[3];
}

// ---- K4: final reduce ----
__global__ __launch_bounds__(256)
void pinn_reduce_kernel(const float* __restrict__ partials, int nblocks,
                        float* __restrict__ out, float scale) {
    __shared__ float ws[4];
    const int t = threadIdx.x;
    float v = 0.0f;
    for (int i = t; i < nblocks; i += 256) v += partials[i];
    #pragma unroll
    for (int off = 32; off > 0; off >>= 1) v += __shfl_down(v, off, 64);
    if ((t & 63) == 0) ws[t >> 6] = v;
    __syncthreads();
    if (t == 0) out[0] = (ws[0] + ws[1] + ws[2] + ws[3]) * scale;
}

extern "C" void kernel_launch(void* const* d_in, const int* in_sizes, int n_in,
                              void* d_out, int out_size, void* d_ws, size_t ws_size,
                              hipStream_t stream) {
    const float* x  = (const float*)d_in[0];
    const float* W1 = (const float*)d_in[1];
    const float* b1 = (const float*)d_in[2];
    const float* W2 = (const float*)d_in[3];
    const float* b2 = (const float*)d_in[4];
    const float* W3 = (const float*)d_in[5];
    const float* b3 = (const float*)d_in[6];
    const float* W4 = (const float*)d_in[7];
    // d_in[8] = b4: constant offset; vanishes under d^4/dx^4.

    const int n = in_sizes[0];
    const int nblocks = (n + 255) / 256;

    float* ws       = (float*)d_ws;
    float* f_nodes  = ws;                 // 64 floats
    float* coeffs   = ws + M_NODES;       // 64 floats
    float* partials = ws + 2 * M_NODES;   // nblocks floats

    pinn_node_kernel<<<16, 256, 0, stream>>>(W1, b1, W2, b2, W3, b3, W4, f_nodes);
    pinn_dct_kernel<<<1, 64, 0, stream>>>(f_nodes, coeffs);
    pinn_eval_kernel<<<nblocks, 256, 0, stream>>>(x, coeffs, partials, n);
    pinn_reduce_kernel<<<1, 256, 0, stream>>>(partials, nblocks, (float*)d_out,
                                              1.0f / (float)n);
}